// Round 1
// baseline (589.016 us; speedup 1.0000x reference)
//
#include <hip/hip_runtime.h>

// LSTM predictor: B=1024 batch, T=1024 steps, H=51 hidden, input_size=1.
// Decomposition: one wave (64 lanes) per batch element; lane l owns hidden
// unit l (l<51). Each lane keeps its 4 rows of W_hh (204 floats) in VGPRs
// (1 wave/SIMD -> up to 512 VGPRs, no spill). Per step, h[k] is broadcast
// from lane k via v_readlane; state update (c,h) is fully lane-local.
// Per-step fc output (h . fc_w) is staged in LDS (stride 65 -> bank-conflict
// free) and reduced + stored coalesced every 64 steps.

#define HID 51
#define SEQ_T 1024

__device__ __forceinline__ float lane_bcast(float v, int lane) {
    return __int_as_float(__builtin_amdgcn_readlane(__float_as_int(v), lane));
}

// sigmoid(x) = 1 / (1 + 2^(-x*log2e)); graceful at extremes (inf->0, 0->1)
__device__ __forceinline__ float fast_sigmoid(float x) {
    float e = __builtin_amdgcn_exp2f(x * -1.44269504088896340736f);
    return __builtin_amdgcn_rcpf(1.0f + e);
}

// tanh(x) = 1 - 2/(2^(2x*log2e) + 1); extremes: +inf->1, 0->-1 (x<<0)
__device__ __forceinline__ float fast_tanh(float x) {
    float e = __builtin_amdgcn_exp2f(x * 2.88539008177792681472f);
    return 1.0f - 2.0f * __builtin_amdgcn_rcpf(e + 1.0f);
}

__global__ __launch_bounds__(64, 1) void lstm_wave_kernel(
    const float* __restrict__ x,      // [B, T]
    const float* __restrict__ W_ih,   // [4H, 1]
    const float* __restrict__ W_hh,   // [4H, H]
    const float* __restrict__ b_ih,   // [4H]
    const float* __restrict__ b_hh,   // [4H]
    const float* __restrict__ fc_w,   // [1, H]
    const float* __restrict__ fc_b,   // [1]
    float* __restrict__ out)          // [B, T]
{
    const int b = blockIdx.x;
    const int l = threadIdx.x;
    const bool act = (l < HID);

    // per-64-step output staging: pbuf[lane][step]; stride 65 words ->
    // bank (65*l + i) % 32 = (l+i) % 32: conflict-free write & read.
    __shared__ float pbuf[64][65];

    // ---- one-time parameter load (cached in L2/L3; ~42KB per wave) ----
    float wi[HID], wf[HID], wg[HID], wo[HID];
#pragma unroll
    for (int k = 0; k < HID; ++k) {
        wi[k] = act ? W_hh[(0 * HID + l) * HID + k] : 0.0f;
        wf[k] = act ? W_hh[(1 * HID + l) * HID + k] : 0.0f;
        wg[k] = act ? W_hh[(2 * HID + l) * HID + k] : 0.0f;
        wo[k] = act ? W_hh[(3 * HID + l) * HID + k] : 0.0f;
    }
    float bi = 0.f, bf = 0.f, bg = 0.f, bo = 0.f;
    float wxi = 0.f, wxf = 0.f, wxg = 0.f, wxo = 0.f, fcw = 0.f;
    if (act) {
        bi = b_ih[0 * HID + l] + b_hh[0 * HID + l];
        bf = b_ih[1 * HID + l] + b_hh[1 * HID + l];
        bg = b_ih[2 * HID + l] + b_hh[2 * HID + l];
        bo = b_ih[3 * HID + l] + b_hh[3 * HID + l];
        wxi = W_ih[0 * HID + l];
        wxf = W_ih[1 * HID + l];
        wxg = W_ih[2 * HID + l];
        wxo = W_ih[3 * HID + l];
        fcw = fc_w[l];
    }
    const float fcb = fc_b[0];

    float h = 0.0f, c = 0.0f;

#pragma unroll 1
    for (int t0 = 0; t0 < SEQ_T; t0 += 64) {
        // prefetch 64 steps of x for this batch element (coalesced)
        const float xv = x[b * SEQ_T + t0 + l];

#pragma unroll 1
        for (int i = 0; i < 64; ++i) {
            const float xt = lane_bcast(xv, i);  // uniform step input
            float ai = fmaf(xt, wxi, bi);
            float af = fmaf(xt, wxf, bf);
            float ag = fmaf(xt, wxg, bg);
            float ao = fmaf(xt, wxo, bo);
#pragma unroll
            for (int k = 0; k < HID; ++k) {
                const float hb = lane_bcast(h, k);  // h[k] from lane k
                ai = fmaf(hb, wi[k], ai);
                af = fmaf(hb, wf[k], af);
                ag = fmaf(hb, wg[k], ag);
                ao = fmaf(hb, wo[k], ao);
            }
            const float ig = fast_sigmoid(ai);
            const float fg = fast_sigmoid(af);
            const float gg = fast_tanh(ag);
            const float og = fast_sigmoid(ao);
            c = fmaf(fg, c, ig * gg);
            h = og * fast_tanh(c);
            // lanes >= HID have all-zero params: h stays 0, contributes 0.
            pbuf[l][i] = h * fcw;
        }

        __syncthreads();
        float s = 0.0f;
#pragma unroll
        for (int k = 0; k < HID; ++k) s += pbuf[k][l];
        out[b * SEQ_T + t0 + l] = s + fcb;  // coalesced, 64 outputs/chunk
        __syncthreads();
    }
}

extern "C" void kernel_launch(void* const* d_in, const int* in_sizes, int n_in,
                              void* d_out, int out_size, void* d_ws, size_t ws_size,
                              hipStream_t stream) {
    (void)in_sizes; (void)n_in; (void)d_ws; (void)ws_size; (void)out_size;
    const float* x    = (const float*)d_in[0];
    const float* W_ih = (const float*)d_in[1];
    const float* W_hh = (const float*)d_in[2];
    const float* b_ih = (const float*)d_in[3];
    const float* b_hh = (const float*)d_in[4];
    const float* fc_w = (const float*)d_in[5];
    const float* fc_b = (const float*)d_in[6];
    float* out = (float*)d_out;

    lstm_wave_kernel<<<dim3(1024), dim3(64), 0, stream>>>(
        x, W_ih, W_hh, b_ih, b_hh, fc_w, fc_b, out);
}

// Round 2
// 569.703 us; speedup vs baseline: 1.0339x; 1.0339x over previous
//
#include <hip/hip_runtime.h>

// LSTM predictor: B=1024 batch, T=1024 steps, H=51 hidden, input_size=1.
// One wave (64 lanes) per batch element; lane l owns hidden unit l (l<51).
// Lane keeps its 4 rows of W_hh (204 floats) register-resident -- enforced
// with asm pins, since the compiler's pressure heuristic otherwise sinks
// the loads into the t-loop (round-1: VGPR_Count=120 < 204 needed, and
// ~850 extra cycles/step of memory traffic). 1 wave/SIMD -> 512-reg
// unified VGPR/AGPR budget, ~235 live fits without scratch spill.
// h[k] broadcast via v_readlane; c,h update lane-local. Per-step fc output
// staged in LDS (stride 65, conflict-free), reduced+stored every 64 steps.

#define HID 51
#define SEQ_T 1024

__device__ __forceinline__ float lane_bcast(float v, int lane) {
    return __int_as_float(__builtin_amdgcn_readlane(__float_as_int(v), lane));
}

// sigmoid(x) = 1 / (1 + 2^(-x*log2e)); graceful at extremes (inf->0, 0->1)
__device__ __forceinline__ float fast_sigmoid(float x) {
    float e = __builtin_amdgcn_exp2f(x * -1.44269504088896340736f);
    return __builtin_amdgcn_rcpf(1.0f + e);
}

// tanh(x) = 1 - 2/(2^(2x*log2e) + 1); extremes: +inf->1, -inf->-1
__device__ __forceinline__ float fast_tanh(float x) {
    float e = __builtin_amdgcn_exp2f(x * 2.88539008177792681472f);
    return 1.0f - 2.0f * __builtin_amdgcn_rcpf(e + 1.0f);
}

__global__ __launch_bounds__(64, 1) void lstm_wave_kernel(
    const float* __restrict__ x,      // [B, T]
    const float* __restrict__ W_ih,   // [4H, 1]
    const float* __restrict__ W_hh,   // [4H, H]
    const float* __restrict__ b_ih,   // [4H]
    const float* __restrict__ b_hh,   // [4H]
    const float* __restrict__ fc_w,   // [1, H]
    const float* __restrict__ fc_b,   // [1]
    float* __restrict__ out)          // [B, T]
{
    const int b = blockIdx.x;
    const int l = threadIdx.x;
    const bool act = (l < HID);

    // per-64-step output staging: pbuf[lane][step]; stride 65 words ->
    // bank (65*l + i) % 32 = (l+i) % 32: conflict-free write & read.
    __shared__ float pbuf[64][65];

    // ---- one-time parameter load, pinned into registers ----
    float wi[HID], wf[HID], wg[HID], wo[HID];
#pragma unroll
    for (int k = 0; k < HID; ++k) {
        wi[k] = act ? W_hh[(0 * HID + l) * HID + k] : 0.0f;
        wf[k] = act ? W_hh[(1 * HID + l) * HID + k] : 0.0f;
        wg[k] = act ? W_hh[(2 * HID + l) * HID + k] : 0.0f;
        wo[k] = act ? W_hh[(3 * HID + l) * HID + k] : 0.0f;
        // Opaque-ify: the compiler cannot rematerialize/sink these loads;
        // the values must stay live in the 512-reg VGPR/AGPR file.
        asm volatile("" : "+v"(wi[k]), "+v"(wf[k]), "+v"(wg[k]), "+v"(wo[k]));
    }
    float bi = 0.f, bf = 0.f, bg = 0.f, bo = 0.f;
    float wxi = 0.f, wxf = 0.f, wxg = 0.f, wxo = 0.f, fcw = 0.f;
    if (act) {
        bi = b_ih[0 * HID + l] + b_hh[0 * HID + l];
        bf = b_ih[1 * HID + l] + b_hh[1 * HID + l];
        bg = b_ih[2 * HID + l] + b_hh[2 * HID + l];
        bo = b_ih[3 * HID + l] + b_hh[3 * HID + l];
        wxi = W_ih[0 * HID + l];
        wxf = W_ih[1 * HID + l];
        wxg = W_ih[2 * HID + l];
        wxo = W_ih[3 * HID + l];
        fcw = fc_w[l];
    }
    asm volatile("" : "+v"(bi), "+v"(bf), "+v"(bg), "+v"(bo));
    asm volatile("" : "+v"(wxi), "+v"(wxf), "+v"(wxg), "+v"(wxo), "+v"(fcw));
    const float fcb = fc_b[0];

    float h = 0.0f, c = 0.0f;

#pragma unroll 1
    for (int t0 = 0; t0 < SEQ_T; t0 += 64) {
        // prefetch 64 steps of x for this batch element (coalesced)
        const float xv = x[b * SEQ_T + t0 + l];

#pragma unroll 1
        for (int i = 0; i < 64; ++i) {
            const float xt = lane_bcast(xv, i);  // uniform step input
            float ai = fmaf(xt, wxi, bi);
            float af = fmaf(xt, wxf, bf);
            float ag = fmaf(xt, wxg, bg);
            float ao = fmaf(xt, wxo, bo);
#pragma unroll
            for (int k = 0; k < HID; ++k) {
                const float hb = lane_bcast(h, k);  // h[k] from lane k
                ai = fmaf(hb, wi[k], ai);
                af = fmaf(hb, wf[k], af);
                ag = fmaf(hb, wg[k], ag);
                ao = fmaf(hb, wo[k], ao);
            }
            const float ig = fast_sigmoid(ai);
            const float fg = fast_sigmoid(af);
            const float gg = fast_tanh(ag);
            const float og = fast_sigmoid(ao);
            c = fmaf(fg, c, ig * gg);
            h = og * fast_tanh(c);
            // lanes >= HID have all-zero params: h stays 0, contributes 0.
            pbuf[l][i] = h * fcw;
        }

        __syncthreads();
        float s = 0.0f;
#pragma unroll
        for (int k = 0; k < HID; ++k) s += pbuf[k][l];
        out[b * SEQ_T + t0 + l] = s + fcb;  // coalesced, 64 outputs/chunk
        __syncthreads();
    }
}

extern "C" void kernel_launch(void* const* d_in, const int* in_sizes, int n_in,
                              void* d_out, int out_size, void* d_ws, size_t ws_size,
                              hipStream_t stream) {
    (void)in_sizes; (void)n_in; (void)d_ws; (void)ws_size; (void)out_size;
    const float* x    = (const float*)d_in[0];
    const float* W_ih = (const float*)d_in[1];
    const float* W_hh = (const float*)d_in[2];
    const float* b_ih = (const float*)d_in[3];
    const float* b_hh = (const float*)d_in[4];
    const float* fc_w = (const float*)d_in[5];
    const float* fc_b = (const float*)d_in[6];
    float* out = (float*)d_out;

    lstm_wave_kernel<<<dim3(1024), dim3(64), 0, stream>>>(
        x, W_ih, W_hh, b_ih, b_hh, fc_w, fc_b, out);
}

// Round 3
// 567.109 us; speedup vs baseline: 1.0386x; 1.0046x over previous
//
#include <hip/hip_runtime.h>

// LSTM predictor: B=1024 batch, T=1024 steps, H=51 hidden, input_size=1.
// One wave (64 lanes) per batch element; lane l owns hidden unit l (l<51).
// Lane keeps its 4 rows of W_hh (204 floats) register-resident.
//   Round-1 lesson: compiler sinks the loads into the loop (VGPR=120).
//   Round-2 lesson: asm pins alone don't help -- the allocator SPILLS the
//   pinned values to scratch to honor its default ~4-waves/EU occupancy
//   target (<=128 VGPR). Fix: amdgpu_waves_per_eu(1,1) pins occupancy at
//   1 wave/SIMD (which the 1024-wave launch is anyway), unlocking the
//   256-arch-VGPR budget. ~220 live regs needed -> fits, no spill.
// h[k] broadcast via v_readlane (imm lane after unroll); c,h lane-local.
// Per-step fc output staged in LDS (stride 65, conflict-free), reduced and
// stored coalesced every 64 steps.

#define HID 51
#define SEQ_T 1024

__device__ __forceinline__ float lane_bcast(float v, int lane) {
    return __int_as_float(__builtin_amdgcn_readlane(__float_as_int(v), lane));
}

// sigmoid(x) = 1 / (1 + 2^(-x*log2e)); graceful at extremes (inf->0, 0->1)
__device__ __forceinline__ float fast_sigmoid(float x) {
    float e = __builtin_amdgcn_exp2f(x * -1.44269504088896340736f);
    return __builtin_amdgcn_rcpf(1.0f + e);
}

// tanh(x) = 1 - 2/(2^(2x*log2e) + 1); extremes: +inf->1, -inf->-1
__device__ __forceinline__ float fast_tanh(float x) {
    float e = __builtin_amdgcn_exp2f(x * 2.88539008177792681472f);
    return 1.0f - 2.0f * __builtin_amdgcn_rcpf(e + 1.0f);
}

__global__ __launch_bounds__(64)
__attribute__((amdgpu_waves_per_eu(1, 1)))
void lstm_wave_kernel(
    const float* __restrict__ x,      // [B, T]
    const float* __restrict__ W_ih,   // [4H, 1]
    const float* __restrict__ W_hh,   // [4H, H]
    const float* __restrict__ b_ih,   // [4H]
    const float* __restrict__ b_hh,   // [4H]
    const float* __restrict__ fc_w,   // [1, H]
    const float* __restrict__ fc_b,   // [1]
    float* __restrict__ out)          // [B, T]
{
    const int b = blockIdx.x;
    const int l = threadIdx.x;
    const bool act = (l < HID);

    // per-64-step output staging: pbuf[lane][step]; stride 65 words ->
    // bank (65*l + i) % 32 = (l+i) % 32: conflict-free write & read.
    __shared__ float pbuf[64][65];

    // ---- one-time parameter load, pinned into registers ----
    float wi[HID], wf[HID], wg[HID], wo[HID];
#pragma unroll
    for (int k = 0; k < HID; ++k) {
        wi[k] = act ? W_hh[(0 * HID + l) * HID + k] : 0.0f;
        wf[k] = act ? W_hh[(1 * HID + l) * HID + k] : 0.0f;
        wg[k] = act ? W_hh[(2 * HID + l) * HID + k] : 0.0f;
        wo[k] = act ? W_hh[(3 * HID + l) * HID + k] : 0.0f;
        // Opaque-ify so the loads can't be rematerialized/sunk; with the
        // waves_per_eu(1,1) budget the allocator keeps them resident.
        asm volatile("" : "+v"(wi[k]), "+v"(wf[k]), "+v"(wg[k]), "+v"(wo[k]));
    }
    float bi = 0.f, bf = 0.f, bg = 0.f, bo = 0.f;
    float wxi = 0.f, wxf = 0.f, wxg = 0.f, wxo = 0.f, fcw = 0.f;
    if (act) {
        bi = b_ih[0 * HID + l] + b_hh[0 * HID + l];
        bf = b_ih[1 * HID + l] + b_hh[1 * HID + l];
        bg = b_ih[2 * HID + l] + b_hh[2 * HID + l];
        bo = b_ih[3 * HID + l] + b_hh[3 * HID + l];
        wxi = W_ih[0 * HID + l];
        wxf = W_ih[1 * HID + l];
        wxg = W_ih[2 * HID + l];
        wxo = W_ih[3 * HID + l];
        fcw = fc_w[l];
    }
    asm volatile("" : "+v"(bi), "+v"(bf), "+v"(bg), "+v"(bo));
    asm volatile("" : "+v"(wxi), "+v"(wxf), "+v"(wxg), "+v"(wxo), "+v"(fcw));
    const float fcb = fc_b[0];

    float h = 0.0f, c = 0.0f;

#pragma unroll 1
    for (int t0 = 0; t0 < SEQ_T; t0 += 64) {
        // prefetch 64 steps of x for this batch element (coalesced)
        const float xv = x[b * SEQ_T + t0 + l];

#pragma unroll 1
        for (int i = 0; i < 64; ++i) {
            const float xt = lane_bcast(xv, i);  // uniform step input
            float ai = fmaf(xt, wxi, bi);
            float af = fmaf(xt, wxf, bf);
            float ag = fmaf(xt, wxg, bg);
            float ao = fmaf(xt, wxo, bo);
#pragma unroll
            for (int k = 0; k < HID; ++k) {
                const float hb = lane_bcast(h, k);  // h[k] from lane k
                ai = fmaf(hb, wi[k], ai);
                af = fmaf(hb, wf[k], af);
                ag = fmaf(hb, wg[k], ag);
                ao = fmaf(hb, wo[k], ao);
            }
            const float ig = fast_sigmoid(ai);
            const float fg = fast_sigmoid(af);
            const float gg = fast_tanh(ag);
            const float og = fast_sigmoid(ao);
            c = fmaf(fg, c, ig * gg);
            h = og * fast_tanh(c);
            // lanes >= HID have all-zero params: h stays 0, contributes 0.
            pbuf[l][i] = h * fcw;
        }

        __syncthreads();
        float s = 0.0f;
#pragma unroll
        for (int k = 0; k < HID; ++k) s += pbuf[k][l];
        out[b * SEQ_T + t0 + l] = s + fcb;  // coalesced, 64 outputs/chunk
        __syncthreads();
    }
}

extern "C" void kernel_launch(void* const* d_in, const int* in_sizes, int n_in,
                              void* d_out, int out_size, void* d_ws, size_t ws_size,
                              hipStream_t stream) {
    (void)in_sizes; (void)n_in; (void)d_ws; (void)ws_size; (void)out_size;
    const float* x    = (const float*)d_in[0];
    const float* W_ih = (const float*)d_in[1];
    const float* W_hh = (const float*)d_in[2];
    const float* b_ih = (const float*)d_in[3];
    const float* b_hh = (const float*)d_in[4];
    const float* fc_w = (const float*)d_in[5];
    const float* fc_b = (const float*)d_in[6];
    float* out = (float*)d_out;

    lstm_wave_kernel<<<dim3(1024), dim3(64), 0, stream>>>(
        x, W_ih, W_hh, b_ih, b_hh, fc_w, fc_b, out);
}